// Round 1
// baseline (329.133 us; speedup 1.0000x reference)
//
#include <hip/hip_runtime.h>

// SoftDTW: B=64 batches, M=N=512, gamma=0.01, P=2.
// R[i,j] = d[i,j] + softmin_g(R[i-1,j-1], R[i-1,j], R[i,j-1]),
// d[i,j] = (x[b,j] - y[b,i])^2, output R[M-1,N-1] per batch.
//
// One block per batch, one thread per column j. Anti-diagonal wavefront:
// diag d holds cells (i = d - j, j). 3 rotating LDS diagonal buffers.

#define BIGF 1e30f

__global__ __launch_bounds__(512) void softdtw_kernel(
    const float* __restrict__ x, const float* __restrict__ y,
    float* __restrict__ out)
{
    constexpr int N = 512;
    const int b = blockIdx.x;
    const int j = threadIdx.x;

    __shared__ float ylds[N];
    __shared__ float Rb[3][N];

    const float xj = x[b * N + j];
    ylds[j] = y[b * N + j];
    __syncthreads();

    // softmin_g(a,b,c) = m - g*ln(sum exp((m-a_i)/g)), m = min
    // exp((m-a)/g) = exp2((m-a) * K), K = (1/g)*log2(e) = 100*1.442695...
    // g*ln(S) = g*ln2*log2(S) = C*log2(S), C = 0.01*ln(2)
    const float K = 144.26950408889634f;
    const float C = 0.006931471805599453f;

    int cur = 0, p1 = 2, p2 = 1;  // cur = d%3, p1 = (d-1)%3, p2 = (d-2)%3
    float result = 0.0f;

    for (int d = 0; d < 2 * N - 1; ++d) {
        const int i = d - j;
        if (i >= 0 && i < N) {
            float diff = xj - ylds[i];
            float dij = diff * diff;

            float rd = (i > 0 && j > 0) ? Rb[p2][j - 1]
                     : ((i == 0 && j == 0) ? 0.0f : BIGF);
            float ru = (i > 0) ? Rb[p1][j] : BIGF;
            float rl = (j > 0) ? Rb[p1][j - 1] : BIGF;

            float m = fminf(rd, fminf(ru, rl));
            float s = exp2f((m - rd) * K)
                    + exp2f((m - ru) * K)
                    + exp2f((m - rl) * K);
            float r = dij + m - C * log2f(s);

            Rb[cur][j] = r;
            result = r;
        }
        __syncthreads();
        int t = p2; p2 = p1; p1 = cur; cur = t;
    }

    if (j == N - 1) out[b] = result;  // thread 511's last cell is (511,511)
}

extern "C" void kernel_launch(void* const* d_in, const int* in_sizes, int n_in,
                              void* d_out, int out_size, void* d_ws, size_t ws_size,
                              hipStream_t stream) {
    const float* x = (const float*)d_in[0];  // [64, 512]
    const float* y = (const float*)d_in[1];  // [64, 512]
    float* out = (float*)d_out;              // [64]
    softdtw_kernel<<<64, 512, 0, stream>>>(x, y, out);
}